// Round 5
// baseline (20.283 us; speedup 1.0000x reference)
//
#include <hip/hip_runtime.h>

#define B_    2
#define H1_   54
#define W1_   120
#define HW_   (H1_*W1_)      // 6480
#define NPIX  (B_*HW_)       // 12960
#define H2_   54
#define W2_   120
#define MAPSZ (H2_*W2_)      // 6480
#define KNUM  81
#define UPF   8
#define PPB   32             // pixels per corr block
#define WSTR  101            // per-pixel window stride (odd -> <=2-way LDS, free)
#define CORR_BLOCKS ((NPIX + PPB - 1)/PPB)       // 405
#define UP_BLOCKS   (B_*H1_*UPF*4)               // 3456: (n,h,uy,wq), 1 softmax/thread

__global__ __launch_bounds__(256) void fused_kernel(
    const float* __restrict__ cost_maps,   // (NPIX, 1, 54, 120)
    const float* __restrict__ coords,      // (B, 2, H1, W1)
    const float* __restrict__ flow,        // (B, 2, H1, W1)
    const float* __restrict__ mask,        // (B, 576, H1, W1)
    float* __restrict__ corr_out,          // (B, 81, H1, W1)
    float* __restrict__ up_out)            // (B, 2, 432, 960)
{
    const int t = threadIdx.x;

    if (blockIdx.x < UP_BLOCKS) {
        // ============ flow upsample: 1 softmax per thread ============
        __shared__ float s_up[2][240];     // [ch][wi*8+ux]
        int ub = blockIdx.x;
        int wq = ub & 3;  ub >>= 2;
        int uy = ub & 7;  ub >>= 3;
        int h  = ub % H1_;
        int n  = ub / H1_;

        if (t < 240) {
            int ux = t / 30;
            int wi = t - ux * 30;
            int w  = wq * 30 + wi;

            // 3x3 neighborhood of 8*flow, zero-padded (L1/L2-hot: 3 rows/block)
            float nb0[9], nb1[9];
#pragma unroll
            for (int i = 0; i < 3; ++i) {
#pragma unroll
                for (int j = 0; j < 3; ++j) {
                    int yy = h + i - 1, xx = w + j - 1;
                    bool v = (yy >= 0) && (yy < H1_) && (xx >= 0) && (xx < W1_);
                    int yc = min(max(yy, 0), H1_ - 1);
                    int xc = min(max(xx, 0), W1_ - 1);
                    float f0 = flow[((size_t)(n * 2 + 0) * H1_ + yc) * W1_ + xc];
                    float f1 = flow[((size_t)(n * 2 + 1) * H1_ + yc) * W1_ + xc];
                    nb0[i * 3 + j] = v ? 8.f * f0 : 0.f;
                    nb1[i * 3 + j] = v ? 8.f * f1 : 0.f;
                }
            }

            // 9 coalesced mask loads: c = k*64 + uy*8 + ux
            float mv[9];
            const float* __restrict__ mb =
                mask + ((size_t)n * 576 + uy * 8 + ux) * HW_ + h * W1_ + w;
#pragma unroll
            for (int k = 0; k < 9; ++k)
                mv[k] = mb[(size_t)k * 64 * HW_];

            float mmax = mv[0];
#pragma unroll
            for (int k = 1; k < 9; ++k) mmax = fmaxf(mmax, mv[k]);
            float s = 0.f;
#pragma unroll
            for (int k = 0; k < 9; ++k) { mv[k] = __expf(mv[k] - mmax); s += mv[k]; }
            float inv = 1.f / s;
            float a0 = 0.f, a1 = 0.f;
#pragma unroll
            for (int k = 0; k < 9; ++k) { a0 += mv[k] * nb0[k]; a1 += mv[k] * nb1[k]; }
            s_up[0][wi * 8 + ux] = a0 * inv;
            s_up[1][wi * 8 + ux] = a1 * inv;
        }
        __syncthreads();

        // coalesced float4 stores via LDS transpose:
        // wave0 lanes 0-59 -> ch0, wave1 lanes 64-123 -> ch1
        {
            int ch = t >> 6;           // 0 or 1 for active range
            int j  = t & 63;
            if (ch < 2 && j < 60) {
                int wi  = j >> 1;
                int uxh = j & 1;
                float4 v = *(float4*)&s_up[ch][wi * 8 + uxh * 4];
                const int HO = H1_ * UPF, WO = W1_ * UPF;
                size_t base = ((size_t)(n * 2 + ch) * HO + (h * UPF + uy)) * WO
                            + (size_t)(wq * 30 + wi) * UPF + uxh * 4;
                *(float4*)(up_out + base) = v;
            }
        }
    } else {
        // ================= corr: encode_flow_token =================
        __shared__ float win[PPB * WSTR];      // 12,928 B
        __shared__ float s_wx[PPB], s_wy[PPB];
        __shared__ int   s_xb[PPB], s_yb[PPB];

        const int pix0   = (blockIdx.x - UP_BLOCKS) * PPB;
        const int nvalid = min(PPB, NPIX - pix0);

        // phase A: per-pixel meta (weights k-invariant: frac(cx+int)=frac(cx))
        if (t < nvalid) {
            int pix = pix0 + t;
            int b   = pix / HW_;
            int r   = pix - b * HW_;
            float cx = coords[(size_t)b * 2 * HW_ + r];
            float cy = coords[(size_t)b * 2 * HW_ + HW_ + r];
            float fx = floorf(cx), fy = floorf(cy);
            s_wx[t] = cx - fx;
            s_wy[t] = cy - fy;
            s_xb[t] = (int)fx - 4;
            s_yb[t] = (int)fy - 4;
        }
        __syncthreads();

        // phase B: stage 10x10 window per pixel into LDS; OOB taps -> 0
        {
            int p = t >> 3;          // 8 threads per pixel
            int s = t & 7;
            if (p < nvalid) {
                const float* __restrict__ mp = cost_maps + (size_t)(pix0 + p) * MAPSZ;
                int xb = s_xb[p], yb = s_yb[p];
                float* wp = win + p * WSTR;
#pragma unroll
                for (int j = 0; j < 13; ++j) {
                    int rc = 8 * j + s;             // 0..103
                    if (rc < 100) {
                        int rr = rc / 10;
                        int cc = rc - rr * 10;
                        int row = yb + rr, col = xb + cc;
                        bool v  = ((unsigned)row < (unsigned)H2_) &&
                                  ((unsigned)col < (unsigned)W2_);
                        int rcl = min(max(row, 0), H2_ - 1);
                        int ccl = min(max(col, 0), W2_ - 1);
                        float val = mp[rcl * W2_ + ccl];
                        wp[rc] = v ? val : 0.f;
                    }
                }
            }
        }
        __syncthreads();

        // phase C: 4 LDS reads + 4 FMA per output; stores coalesced over p
        {
            int p = t & 31;
            int q = t >> 5;          // 0..7
            if (p < nvalid) {
                int pix = pix0 + p;
                int b   = pix / HW_;
                int r   = pix - b * HW_;
                float wx = s_wx[p], wy = s_wy[p];
                float w00 = (1.f - wx) * (1.f - wy);
                float w10 = wx * (1.f - wy);
                float w01 = (1.f - wx) * wy;
                float w11 = wx * wy;
                const float* __restrict__ wp = win + p * WSTR;
                float* __restrict__ ob = corr_out + (size_t)b * KNUM * HW_ + r;
#pragma unroll
                for (int j = 0; j < 11; ++j) {
                    int k = q + 8 * j;
                    if (k < KNUM) {
                        int iy = k / 9;
                        int ix = k - 9 * iy;
                        const float* w0 = wp + ix * 10 + iy;
                        float v00 = w0[0], v10 = w0[1];
                        float v01 = w0[10], v11 = w0[11];
                        ob[(size_t)k * HW_] =
                            w00 * v00 + w10 * v10 + w01 * v01 + w11 * v11;
                    }
                }
            }
        }
    }
}

extern "C" void kernel_launch(void* const* d_in, const int* in_sizes, int n_in,
                              void* d_out, int out_size, void* d_ws, size_t ws_size,
                              hipStream_t stream) {
    const float* cost_maps = (const float*)d_in[0];
    const float* coords    = (const float*)d_in[1];
    const float* flow      = (const float*)d_in[2];
    const float* mask      = (const float*)d_in[3];
    float* out = (float*)d_out;

    const int corr_total = B_ * KNUM * HW_;   // 1,049,760
    fused_kernel<<<UP_BLOCKS + CORR_BLOCKS, 256, 0, stream>>>(
        cost_maps, coords, flow, mask, out, out + corr_total);
}

// Round 6
// 15.622 us; speedup vs baseline: 1.2984x; 1.2984x over previous
//
#include <hip/hip_runtime.h>

#define B_    2
#define H1_   54
#define W1_   120
#define HW_   (H1_*W1_)      // 6480
#define NPIX  (B_*HW_)       // 12960
#define H2_   54
#define W2_   120
#define MAPSZ (H2_*W2_)      // 6480
#define KNUM  81
#define UPF   8
#define PPB   32             // pixels per corr block
#define WSTR  101            // per-pixel window stride (odd -> <=2-way LDS, free)
#define CORR_BLOCKS ((NPIX + PPB - 1)/PPB)   // 405
#define UP_BLOCKS   (B_*H1_*UPF)             // 864: (n,h,uy), 4 ux per thread

__global__ __launch_bounds__(256) void fused_kernel(
    const float* __restrict__ cost_maps,   // (NPIX, 1, 54, 120)
    const float* __restrict__ coords,      // (B, 2, H1, W1)
    const float* __restrict__ flow,        // (B, 2, H1, W1)
    const float* __restrict__ mask,        // (B, 576, H1, W1)
    float* __restrict__ corr_out,          // (B, 81, H1, W1)
    float* __restrict__ up_out)            // (B, 2, 432, 960)
{
    const int t = threadIdx.x;

    if (blockIdx.x < UP_BLOCKS) {
        // ===== flow upsample; all 36 mask loads hoisted (1 mem round-trip) ===
        int ub  = blockIdx.x;
        int uy  = ub % UPF; ub /= UPF;
        int h   = ub % H1_;
        int n   = ub / H1_;
        int uxh = t >> 7;          // 0/1
        int w   = t & 127;
        if (w >= W1_) return;

        const float* __restrict__ mbase =
            mask + ((size_t)n * 576 * HW_) + (size_t)(uy * 8) * HW_ + h * W1_ + w;

        // prefetch ALL mask values for the 4 softmaxes into registers
        float mv[4][9];
#pragma unroll
        for (int uxi = 0; uxi < 4; ++uxi) {
            int ux = uxh * 4 + uxi;
#pragma unroll
            for (int k = 0; k < 9; ++k)
                mv[uxi][k] = mbase[(size_t)(k * 64 + ux) * HW_];
        }

        // 3x3 neighborhood of 8*flow, zero-padded (k = i*3+j); flow L2-hot
        float nb0[9], nb1[9];
#pragma unroll
        for (int i = 0; i < 3; ++i) {
#pragma unroll
            for (int j = 0; j < 3; ++j) {
                int yy = h + i - 1, xx = w + j - 1;
                bool v = (yy >= 0) && (yy < H1_) && (xx >= 0) && (xx < W1_);
                int yc = min(max(yy, 0), H1_ - 1);
                int xc = min(max(xx, 0), W1_ - 1);
                float f0 = flow[((size_t)(n * 2 + 0) * H1_ + yc) * W1_ + xc];
                float f1 = flow[((size_t)(n * 2 + 1) * H1_ + yc) * W1_ + xc];
                nb0[i * 3 + j] = v ? 8.f * f0 : 0.f;
                nb1[i * 3 + j] = v ? 8.f * f1 : 0.f;
            }
        }

        float row0[4], row1[4];
#pragma unroll
        for (int uxi = 0; uxi < 4; ++uxi) {
            float mmax = mv[uxi][0];
#pragma unroll
            for (int k = 1; k < 9; ++k) mmax = fmaxf(mmax, mv[uxi][k]);
            float s = 0.f;
#pragma unroll
            for (int k = 0; k < 9; ++k) { mv[uxi][k] = __expf(mv[uxi][k] - mmax); s += mv[uxi][k]; }
            float inv = 1.f / s;
            float a0 = 0.f, a1 = 0.f;
#pragma unroll
            for (int k = 0; k < 9; ++k) { a0 += mv[uxi][k] * nb0[k]; a1 += mv[uxi][k] * nb1[k]; }
            row0[uxi] = a0 * inv;
            row1[uxi] = a1 * inv;
        }

        const int HO = H1_ * UPF, WO = W1_ * UPF;
        size_t base0 = ((size_t)(n * 2 + 0) * HO + (h * UPF + uy)) * WO
                     + (size_t)w * UPF + uxh * 4;
        size_t base1 = ((size_t)(n * 2 + 1) * HO + (h * UPF + uy)) * WO
                     + (size_t)w * UPF + uxh * 4;
        *(float4*)(up_out + base0) = make_float4(row0[0], row0[1], row0[2], row0[3]);
        *(float4*)(up_out + base1) = make_float4(row1[0], row1[1], row1[2], row1[3]);
    } else {
        // ================= corr: encode_flow_token =================
        __shared__ float win[PPB * WSTR];      // 12,928 B
        __shared__ float s_wx[PPB], s_wy[PPB];
        __shared__ int   s_xb[PPB], s_yb[PPB];

        const int pix0   = (blockIdx.x - UP_BLOCKS) * PPB;
        const int nvalid = min(PPB, NPIX - pix0);

        // phase A: per-pixel meta (weights k-invariant: frac(cx+int)=frac(cx))
        if (t < nvalid) {
            int pix = pix0 + t;
            int b   = pix / HW_;
            int r   = pix - b * HW_;
            float cx = coords[(size_t)b * 2 * HW_ + r];
            float cy = coords[(size_t)b * 2 * HW_ + HW_ + r];
            float fx = floorf(cx), fy = floorf(cy);
            s_wx[t] = cx - fx;
            s_wy[t] = cy - fy;
            s_xb[t] = (int)fx - 4;
            s_yb[t] = (int)fy - 4;
        }
        __syncthreads();

        // phase B: stage 10x10 window per pixel into LDS; OOB taps -> 0
        {
            int p = t >> 3;          // 8 threads per pixel
            int s = t & 7;
            if (p < nvalid) {
                const float* __restrict__ mp = cost_maps + (size_t)(pix0 + p) * MAPSZ;
                int xb = s_xb[p], yb = s_yb[p];
                float* wp = win + p * WSTR;
#pragma unroll
                for (int j = 0; j < 13; ++j) {
                    int rc = 8 * j + s;             // 0..103
                    if (rc < 100) {
                        int rr = rc / 10;
                        int cc = rc - rr * 10;
                        int row = yb + rr, col = xb + cc;
                        bool v  = ((unsigned)row < (unsigned)H2_) &&
                                  ((unsigned)col < (unsigned)W2_);
                        int rcl = min(max(row, 0), H2_ - 1);
                        int ccl = min(max(col, 0), W2_ - 1);
                        float val = mp[rcl * W2_ + ccl];
                        wp[rc] = v ? val : 0.f;
                    }
                }
            }
        }
        __syncthreads();

        // phase C: 4 LDS reads + 4 FMA per output; stores coalesced over p
        {
            int p = t & 31;
            int q = t >> 5;          // 0..7
            if (p < nvalid) {
                int pix = pix0 + p;
                int b   = pix / HW_;
                int r   = pix - b * HW_;
                float wx = s_wx[p], wy = s_wy[p];
                float w00 = (1.f - wx) * (1.f - wy);
                float w10 = wx * (1.f - wy);
                float w01 = (1.f - wx) * wy;
                float w11 = wx * wy;
                const float* __restrict__ wp = win + p * WSTR;
                float* __restrict__ ob = corr_out + (size_t)b * KNUM * HW_ + r;
#pragma unroll
                for (int j = 0; j < 11; ++j) {
                    int k = q + 8 * j;
                    if (k < KNUM) {
                        int iy = k / 9;
                        int ix = k - 9 * iy;
                        const float* w0 = wp + ix * 10 + iy;
                        float v00 = w0[0], v10 = w0[1];
                        float v01 = w0[10], v11 = w0[11];
                        ob[(size_t)k * HW_] =
                            w00 * v00 + w10 * v10 + w01 * v01 + w11 * v11;
                    }
                }
            }
        }
    }
}

extern "C" void kernel_launch(void* const* d_in, const int* in_sizes, int n_in,
                              void* d_out, int out_size, void* d_ws, size_t ws_size,
                              hipStream_t stream) {
    const float* cost_maps = (const float*)d_in[0];
    const float* coords    = (const float*)d_in[1];
    const float* flow      = (const float*)d_in[2];
    const float* mask      = (const float*)d_in[3];
    float* out = (float*)d_out;

    const int corr_total = B_ * KNUM * HW_;   // 1,049,760
    fused_kernel<<<UP_BLOCKS + CORR_BLOCKS, 256, 0, stream>>>(
        cost_maps, coords, flow, mask, out, out + corr_total);
}